// Round 9
// baseline (164.220 us; speedup 1.0000x reference)
//
#include <hip/hip_runtime.h>
#include <hip/hip_bf16.h>

typedef unsigned short u16;
typedef unsigned int   u32;
typedef unsigned long long u64;
typedef __attribute__((ext_vector_type(8))) short short8;   // 8 bf16 (4 VGPRs)
typedef __attribute__((ext_vector_type(4))) float float4v;  // 4 fp32

#define N 8192
#define D 128
#define C 1000
#define TILE 128
#define LDT 136        // padded LDS row stride in bf16
#define NW64 (N / 64)  // 128 packed words per class row
#define JQ 8           // j-tiles per block
#define JW (JQ * 2)    // mask words per row per block
#define NBLK (64 * 8)  // cc_main grid size
#define LOG2E 1.44269504088896340736f

// ---------------------------------------------------------------------------
// Kernel 1 (prep): fused pack + norm, split by block range.
//   blocks [0, 2048): bit-pack negative_mask [N,C] -> packed[l][w]
//   blocks [2048, 4096): per-row L2 normalize -> bf16, proxy term p_i,
//                        zero den/num, zero completion counter.
// ---------------------------------------------------------------------------
__global__ void prep_kernel(const float* __restrict__ nm, u64* __restrict__ packed,
                            const float* __restrict__ x, const float* __restrict__ pr,
                            u16* __restrict__ xnb, float* __restrict__ p_out,
                            float* __restrict__ den, float* __restrict__ num,
                            u32* __restrict__ counter,
                            const float* __restrict__ tp, const float* __restrict__ mp) {
    __shared__ u32 Ls[64 * 65];
    const int bid  = blockIdx.x;
    const int lane = threadIdx.x & 63;
    const int wv   = threadIdx.x >> 6;

    if (bid < 2048) {
        // ---- pack part ----
        const int jt = bid & 127;
        const int lt = bid >> 7;
        const int j0 = jt * 64;
        const int l  = lt * 64 + lane;
        const bool lv = l < C;
        if (bid == 0 && threadIdx.x == 0) counter[0] = 0u;

        #pragma unroll
        for (int rr = 0; rr < 16; rr++) {
            const int r = wv * 16 + rr;
            float v = lv ? nm[(size_t)(j0 + r) * C + l] : 0.0f;
            Ls[r * 65 + lane] = (v > 0.5f) ? 1u : 0u;
        }
        __syncthreads();
        #pragma unroll
        for (int cc = 0; cc < 16; cc++) {
            const int c = wv * 16 + cc;
            u64 m = __ballot(Ls[lane * 65 + c] != 0u);
            if (lane == 0 && (lt * 64 + c) < C)
                packed[(size_t)(lt * 64 + c) * NW64 + jt] = m;
        }
    } else {
        // ---- norm part ----
        const int row = (bid - 2048) * 4 + wv;
        const float2* xr  = (const float2*)(x  + (size_t)row * D);
        const float2* prr = (const float2*)(pr + (size_t)row * D);
        float2 xv = xr[lane];
        float2 pv = prr[lane];

        float sx  = xv.x * xv.x + xv.y * xv.y;
        float sp  = pv.x * pv.x + pv.y * pv.y;
        float sxp = xv.x * pv.x + xv.y * pv.y;
        #pragma unroll
        for (int off = 32; off; off >>= 1) {
            sx  += __shfl_xor(sx,  off);
            sp  += __shfl_xor(sp,  off);
            sxp += __shfl_xor(sxp, off);
        }
        float nx = fmaxf(sqrtf(sx), 1e-8f);
        float np = fmaxf(sqrtf(sp), 1e-8f);
        float inv = 1.0f / nx;

        __hip_bfloat16 b0 = __float2bfloat16(xv.x * inv);
        __hip_bfloat16 b1 = __float2bfloat16(xv.y * inv);
        ((__hip_bfloat162*)xnb)[(size_t)row * 64 + lane] = __halves2bfloat162(b0, b1);

        if (lane == 0) {
            float T = tp[0], M = mp[0];
            p_out[row] = __expf((sxp / (nx * np) - M) / T);
            den[row] = 0.0f;
            num[row] = 0.0f;
        }
    }
}

// ---------------------------------------------------------------------------
// Kernel 2 (cc_main): fused sim-GEMM + exp + mask + per-row sums + final loss.
// R8 structure (A+Ms staged once, ONE barrier, B prefetch rotation, (256,2))
// with (a) r-vectorized float4v epilogue (packed fp32 math), (b) loss computed
// by the last block via completion counter + agent-scope loads.
// ---------------------------------------------------------------------------
template <bool DIAG>
__device__ __forceinline__ void epilogue(const float4v acc[4][4], const u64* __restrict__ Ms,
                                         float4v dacc[4], float4v nacc[4],
                                         int wr, int wc, int kq, int m0,
                                         int ibase, int jbase, int q,
                                         float kA2, float kB2) {
    #pragma unroll
    for (int tm = 0; tm < 4; tm++) {
        // mask word fragments for the 4 rows of this (tm)
        u32 lo[4], hi[4];
        #pragma unroll
        for (int r = 0; r < 4; r++) {
            const int lrow = wr * 64 + tm * 16 + kq * 4 + r;
            const u64 w = Ms[lrow * JW + q * 2 + wc];
            lo[r] = (u32)(w >> m0);
            hi[r] = (u32)(w >> (m0 + 32));
        }
        #pragma unroll
        for (int tn = 0; tn < 4; tn++) {
            float4v t = acc[tm][tn] * kA2 + kB2;      // packed fma pairs
            float4v e;
            #pragma unroll
            for (int r = 0; r < 4; r++) e[r] = __builtin_amdgcn_exp2f(t[r]);
            if (DIAG) {
                const int gj = jbase + wc * 64 + tn * 16 + m0;
                #pragma unroll
                for (int r = 0; r < 4; r++) {
                    const int gi = ibase + wr * 64 + tm * 16 + kq * 4 + r;
                    if (gi == gj) e[r] = 0.0f;
                }
            }
            dacc[tm] += e;                             // packed add pairs
            float4v mf;
            #pragma unroll
            for (int r = 0; r < 4; r++) {
                const u32 bit = ((tn < 2) ? (lo[r] >> (tn * 16)) : (hi[r] >> ((tn - 2) * 16))) & 1u;
                mf[r] = (float)bit;
            }
            nacc[tm] += mf * e;                        // packed fma pairs
        }
    }
}

__global__ __launch_bounds__(256, 2)
void cc_main(const u16* __restrict__ xnb, const int* __restrict__ labels,
             const u64* __restrict__ packed,
             float* __restrict__ den, float* __restrict__ num,
             const float* __restrict__ p_arr, u32* __restrict__ counter,
             float* __restrict__ out,
             const float* __restrict__ tp, const float* __restrict__ mp) {
    __shared__ u16 As[TILE * LDT];    // 34816 B
    __shared__ u64 Ms[TILE * JW];     // 16384 B
    __shared__ u32 done_s;
    __shared__ float red[4];

    const int tid  = threadIdx.x;
    const int lane = tid & 63;
    const int wv   = tid >> 6;
    const int wr   = wv >> 1;
    const int wc   = wv & 1;
    const int m0   = lane & 15;
    const int kq   = lane >> 4;
    const int ibase  = blockIdx.x * TILE;
    const int jsplit = blockIdx.y;
    const int jt0    = jsplit * JQ;

    const float T = tp[0];
    const float M = mp[0];
    const float kA2 = LOG2E / T;
    const float kB2 = -M * LOG2E / T;

    // stage A tile (128 x 128 bf16), each thread 128 B
    {
        const int r = tid >> 1, h = tid & 1;
        const uint4* src = (const uint4*)(xnb + (size_t)(ibase + r) * D + h * 64);
        uint4* dst = (uint4*)(As + r * LDT + h * 64);
        #pragma unroll
        for (int qq = 0; qq < 8; qq++) dst[qq] = src[qq];
    }
    // stage mask words: 128 rows x 16 words for this j-split
    #pragma unroll
    for (int t = 0; t < 8; t++) {
        const int idx = t * 256 + tid;
        const int row = idx >> 4, h = idx & 15;
        const int lab = labels[ibase + row];
        Ms[idx] = packed[(size_t)lab * NW64 + jt0 * 2 + h];
    }
    __syncthreads();

    float4v dacc[4] = {};
    float4v nacc[4] = {};

    const u16* Abase = As + (wr * 64 + m0) * LDT + kq * 8;
    const u16* Blane = xnb + (size_t)(wc * 64 + m0) * D + kq * 8;

    // prefetch (q=0, kk=0)
    short8 bc[4], bn[4];
    {
        const u16* Bp = Blane + (size_t)(jt0 * TILE) * D;
        #pragma unroll
        for (int tn = 0; tn < 4; tn++) bc[tn] = *(const short8*)(Bp + tn * (16 * D));
    }

    for (int q = 0; q < JQ; q++) {
        const int jt = jt0 + q;
        const int jbase = jt * TILE;
        const u16* Bq = Blane + (size_t)jbase * D;

        float4v acc[4][4];
        #pragma unroll
        for (int a = 0; a < 4; a++)
            #pragma unroll
            for (int b = 0; b < 4; b++)
                acc[a][b] = (float4v){0.f, 0.f, 0.f, 0.f};

        #pragma unroll
        for (int kk = 0; kk < 4; kk++) {
            if (kk < 3) {
                #pragma unroll
                for (int tn = 0; tn < 4; tn++)
                    bn[tn] = *(const short8*)(Bq + tn * (16 * D) + (kk + 1) * 32);
            } else if (q < JQ - 1) {
                const u16* Bnq = Bq + (size_t)TILE * D;
                #pragma unroll
                for (int tn = 0; tn < 4; tn++)
                    bn[tn] = *(const short8*)(Bnq + tn * (16 * D));
            }
            short8 a_f[4];
            #pragma unroll
            for (int tm = 0; tm < 4; tm++)
                a_f[tm] = *(const short8*)(Abase + tm * (16 * LDT) + kk * 32);
            #pragma unroll
            for (int tm = 0; tm < 4; tm++)
                #pragma unroll
                for (int tn = 0; tn < 4; tn++)
                    acc[tm][tn] = __builtin_amdgcn_mfma_f32_16x16x32_bf16(
                        a_f[tm], bc[tn], acc[tm][tn], 0, 0, 0);
            #pragma unroll
            for (int tn = 0; tn < 4; tn++) bc[tn] = bn[tn];
        }

        if (jt == blockIdx.x)
            epilogue<true >(acc, Ms, dacc, nacc, wr, wc, kq, m0, ibase, jbase, q, kA2, kB2);
        else
            epilogue<false>(acc, Ms, dacc, nacc, wr, wc, kq, m0, ibase, jbase, q, kA2, kB2);
    }

    // reduce across the 16 column-lanes, then atomics
    #pragma unroll
    for (int tm = 0; tm < 4; tm++) {
        #pragma unroll
        for (int r = 0; r < 4; r++) {
            float d = dacc[tm][r], n = nacc[tm][r];
            #pragma unroll
            for (int off = 1; off < 16; off <<= 1) {
                d += __shfl_xor(d, off);
                n += __shfl_xor(n, off);
            }
            if (m0 == 0) {
                const int gi = ibase + wr * 64 + tm * 16 + kq * 4 + r;
                atomicAdd(&den[gi], d);
                atomicAdd(&num[gi], n);
            }
        }
    }

    // ---- completion counter; last block computes the loss ----
    __threadfence();
    if (tid == 0) done_s = atomicAdd(counter, 1u);
    __syncthreads();
    if (done_s == NBLK - 1) {
        float s = 0.0f;
        #pragma unroll
        for (int t = 0; t < N / 256; t++) {
            const int i = t * 256 + tid;
            float dv = __hip_atomic_load(&den[i], __ATOMIC_RELAXED, __HIP_MEMORY_SCOPE_AGENT);
            float nv = __hip_atomic_load(&num[i], __ATOMIC_RELAXED, __HIP_MEMORY_SCOPE_AGENT);
            float pi = p_arr[i];
            s += -__logf(T * (pi + nv) / (pi + dv));
        }
        #pragma unroll
        for (int off = 32; off; off >>= 1) s += __shfl_xor(s, off);
        if (lane == 0) red[wv] = s;
        __syncthreads();
        if (wv == 0) {
            float tt = (lane < 4) ? red[lane] : 0.0f;
            tt += __shfl_xor(tt, 1);
            tt += __shfl_xor(tt, 2);
            if (lane == 0) out[0] = tt / (float)N;
        }
    }
}

// ---------------------------------------------------------------------------
extern "C" void kernel_launch(void* const* d_in, const int* in_sizes, int n_in,
                              void* d_out, int out_size, void* d_ws, size_t ws_size,
                              hipStream_t stream) {
    (void)in_sizes; (void)n_in; (void)out_size; (void)ws_size;
    const float* inst   = (const float*)d_in[0];
    const float* proxy  = (const float*)d_in[1];
    const float* nm     = (const float*)d_in[2];
    const int*   labels = (const int*)d_in[3];
    const float* temp   = (const float*)d_in[4];
    const float* marg   = (const float*)d_in[5];
    float* out = (float*)d_out;

    char* ws = (char*)d_ws;
    u16*   xnb    = (u16*)ws;                         // N*D*2      = 2,097,152 B
    float* p_arr  = (float*)(ws + 2097152);           // N*4        = 32,768 B
    u64*   packed = (u64*)(ws + 2129920);             // C*128*8    = 1,024,000 B
    float* den    = (float*)(ws + 3153920);           // N*4
    float* num    = (float*)(ws + 3186688);           // N*4
    u32*   cnt    = (u32*)(ws + 3219456);             // 4 B

    prep_kernel<<<4096, 256, 0, stream>>>(nm, packed, inst, proxy, xnb, p_arr,
                                          den, num, cnt, temp, marg);
    cc_main<<<dim3(N / TILE, 8), 256, 0, stream>>>(xnb, labels, packed, den, num,
                                                   p_arr, cnt, out, temp, marg);
}